// Round 5
// baseline (2140.829 us; speedup 1.0000x reference)
//
#include <hip/hip_runtime.h>
#include <hip/hip_bf16.h>
#include <math.h>

// TinyRecursiveModelTRMv3 — Round 5: fused kernel with PERSISTENT latent
// weights in VGPRs (W1 96 + W2 64 regs/wave, loaded once, 20x reuse).
// Latent iterations have no global traffic except x. GEMM2 2m x 4n split.
// ln_z fused into following LN384 phase.

constexpr int NB = 32768;
constexpr int ND = 128;
constexpr float LNEPS = 1e-5f;

typedef short bf16x8 __attribute__((ext_vector_type(8)));
typedef float f32x4 __attribute__((ext_vector_type(4)));
using bf16 = __hip_bfloat16;

static __device__ __forceinline__ float gelu_erf(float x) {
  return 0.5f * x * (1.0f + erff(x * 0.70710678118654752440f));
}
static __device__ __forceinline__ float sigmoidf_(float x) {
  return 1.0f / (1.0f + expf(-x));
}
static __device__ __forceinline__ f32x4 mfma16(bf16x8 a, bf16x8 b, f32x4 c) {
  return __builtin_amdgcn_mfma_f32_16x16x32_bf16(a, b, c, 0, 0, 0);
}
static __device__ __forceinline__ float bf2f(unsigned short u) {
  unsigned v = (unsigned)u << 16;
  return __builtin_bit_cast(float, v);
}
static __device__ __forceinline__ unsigned pk_bf2(float a, float b) {
  unsigned ua = __builtin_bit_cast(unsigned, a);
  unsigned ub = __builtin_bit_cast(unsigned, b);
  ua = (ua + 0x7fffu + ((ua >> 16) & 1u)) >> 16;
  ub = (ub + 0x7fffu + ((ub >> 16) & 1u)) & 0xffff0000u;
  return ub | ua;
}

// fragment-major weight layout: f = ((n>>4)*(K>>5) + (k>>5))*512 + (n&15)*32 + (k&31)
__global__ void prep_w_frag(const float* __restrict__ src, bf16* __restrict__ dst,
                            int K, int N) {
  int i = blockIdx.x * 256 + threadIdx.x;
  if (i >= K * N) return;
  int k = i / N, n = i - k * N;
  int f = ((n >> 4) * (K >> 5) + (k >> 5)) * 512 + (n & 15) * 32 + (k & 31);
  dst[f] = __float2bfloat16(src[i]);
}

__global__ __launch_bounds__(512) void trm_fused(
    const float* __restrict__ x, const float* __restrict__ y_init,
    const float* __restrict__ av_g,
    const float* __restrict__ lnw_lat, const float* __restrict__ lnb_lat,
    const float* __restrict__ lnw_ans, const float* __restrict__ lnb_ans,
    const float* __restrict__ lzw, const float* __restrict__ lzb,
    const bf16* __restrict__ W1F, const float* __restrict__ b1,
    const bf16* __restrict__ W2F, const float* __restrict__ b2,
    const bf16* __restrict__ WA1F, const float* __restrict__ ba1,
    const bf16* __restrict__ WA2F, const float* __restrict__ ba2,
    const float* __restrict__ Wap, const float* __restrict__ bap,
    const float* __restrict__ Wag, const float* __restrict__ bag,
    const bf16* __restrict__ WqF, const float* __restrict__ bq,
    const bf16* __restrict__ WkF, const float* __restrict__ bk,
    const bf16* __restrict__ WvF, const float* __restrict__ bv,
    const float* __restrict__ Wp1, const float* __restrict__ bp1,
    const float* __restrict__ Wp2, const float* __restrict__ bp2,
    float* __restrict__ y_out, float* __restrict__ pad_out,
    float* __restrict__ gate_sum,
    bf16* __restrict__ kh, bf16* __restrict__ vh)
{
  __shared__ __align__(16) char pool[151552];
  __shared__ float sc[64][8];
  __shared__ float gl[64];
  __shared__ float avs[64][3];

  float (* const ys)[132] = (float(*)[132])(pool);
  float (* const zs)[132] = (float(*)[132])(pool + 33792);
  char* const scr = pool + 67584;

  const int t = threadIdx.x;
  const int wave = t >> 6, lane = t & 63;
  const int c = t & 127, rg4 = t >> 7;
  const int row0 = blockIdx.x * 64;
  const int arow = lane & 15;
  const int kseg = (lane >> 4) * 8;
  const int crow = (lane >> 4) * 4;
  const int mg = wave >> 2, ng = wave & 3;  // GEMM2 2m x 4n wave split

  // ===== persistent latent weight registers (loaded once, reused 20x) =====
  bf16x8 w1r[2][12];  // GEMM1: wave covers n-tiles {2w, 2w+1}
#pragma unroll
  for (int ni = 0; ni < 2; ++ni)
#pragma unroll
    for (int kt = 0; kt < 12; ++kt)
      w1r[ni][kt] = *(const bf16x8*)&W1F[(size_t)((wave * 2 + ni) * 12 + kt) * 512 +
                                         arow * 32 + kseg];
  bf16x8 w2r[2][8];   // GEMM2: wave covers n-tiles {2ng, 2ng+1}
#pragma unroll
  for (int ni = 0; ni < 2; ++ni)
#pragma unroll
    for (int kt = 0; kt < 8; ++kt)
      w2r[ni][kt] = *(const bf16x8*)&W2F[(size_t)((2 * ng + ni) * 8 + kt) * 512 +
                                         arow * 32 + kseg];

  auto ln_z = [&]() {
    for (int r = wave; r < 64; r += 8) {
      float2 v = *(const float2*)&zs[r][2 * lane];
      float s = v.x + v.y, ss = v.x * v.x + v.y * v.y;
#pragma unroll
      for (int o = 32; o; o >>= 1) { s += __shfl_xor(s, o); ss += __shfl_xor(ss, o); }
      float m = s * (1.f / 128.f);
      float rstd = rsqrtf(ss * (1.f / 128.f) - m * m + LNEPS);
      float2 w = *(const float2*)&lzw[2 * lane];
      float2 b = *(const float2*)&lzb[2 * lane];
      float2 o2;
      o2.x = (v.x - m) * rstd * w.x + b.x;
      o2.y = (v.y - m) * rstd * w.y + b.y;
      *(float2*)&zs[r][2 * lane] = o2;
    }
  };

  bf16* const li = (bf16*)scr;             // [64][392]
  bf16* const hh = (bf16*)(scr + 50176);   // [64][264]

  // phase A: (optional z-norm) + LN384 -> li
  auto phaseA = [&](bool do_norm) {
    for (int r = wave; r < 64; r += 8) {
      const size_t g = row0 + r;
      float2 xv = *(const float2*)&x[g * ND + 2 * lane];
      float2 yv = *(const float2*)&ys[r][2 * lane];
      float2 zv = *(const float2*)&zs[r][2 * lane];
      if (do_norm) {
        float s = zv.x + zv.y, ss = zv.x * zv.x + zv.y * zv.y;
#pragma unroll
        for (int o = 32; o; o >>= 1) { s += __shfl_xor(s, o); ss += __shfl_xor(ss, o); }
        float m = s * (1.f / 128.f);
        float rstd = rsqrtf(ss * (1.f / 128.f) - m * m + LNEPS);
        float2 w = *(const float2*)&lzw[2 * lane];
        float2 b = *(const float2*)&lzb[2 * lane];
        zv.x = (zv.x - m) * rstd * w.x + b.x;
        zv.y = (zv.y - m) * rstd * w.y + b.y;
        *(float2*)&zs[r][2 * lane] = zv;
      }
      float s = xv.x + xv.y + yv.x + yv.y + zv.x + zv.y;
      float ss = xv.x * xv.x + xv.y * xv.y + yv.x * yv.x + yv.y * yv.y +
                 zv.x * zv.x + zv.y * zv.y;
#pragma unroll
      for (int o = 32; o; o >>= 1) { s += __shfl_xor(s, o); ss += __shfl_xor(ss, o); }
      float m = s * (1.f / 384.f);
      float rstd = rsqrtf(ss * (1.f / 384.f) - m * m + LNEPS);
      float2 w0 = *(const float2*)&lnw_lat[2 * lane];
      float2 bb0 = *(const float2*)&lnb_lat[2 * lane];
      float2 w1 = *(const float2*)&lnw_lat[128 + 2 * lane];
      float2 bb1 = *(const float2*)&lnb_lat[128 + 2 * lane];
      float2 w2 = *(const float2*)&lnw_lat[256 + 2 * lane];
      float2 bb2 = *(const float2*)&lnb_lat[256 + 2 * lane];
      *(unsigned*)&li[r * 392 + 2 * lane] =
          pk_bf2((xv.x - m) * rstd * w0.x + bb0.x, (xv.y - m) * rstd * w0.y + bb0.y);
      *(unsigned*)&li[r * 392 + 128 + 2 * lane] =
          pk_bf2((yv.x - m) * rstd * w1.x + bb1.x, (yv.y - m) * rstd * w1.y + bb1.y);
      *(unsigned*)&li[r * 392 + 256 + 2 * lane] =
          pk_bf2((zv.x - m) * rstd * w2.x + bb2.x, (zv.y - m) * rstd * w2.y + bb2.y);
    }
  };

  // ---- init
#pragma unroll
  for (int r16 = 0; r16 < 16; ++r16) {
    int r = rg4 * 16 + r16;
    ys[r][c] = y_init[(size_t)(row0 + r) * ND + c];
    zs[r][c] = 0.f;
  }
  if (t < 192) ((float*)avs)[t] = av_g[(size_t)row0 * 3 + t];
  __syncthreads();

  for (int k = 0; k < 5; ++k) {
    // ================= 4 latent iterations =================
    for (int n = 0; n < 4; ++n) {
      phaseA(n > 0);   // z entering iter 0 is already normalized (or initial 0)
      __syncthreads();

      // GEMM1: [64x384]@[384x256] -> hh = gelu(.+b1); B from registers
      {
        f32x4 acc[4][2];
#pragma unroll
        for (int mi = 0; mi < 4; ++mi)
#pragma unroll
          for (int ni = 0; ni < 2; ++ni) acc[mi][ni] = (f32x4){0.f, 0.f, 0.f, 0.f};
#pragma unroll
        for (int kt = 0; kt < 12; ++kt) {
          bf16x8 a[4];
#pragma unroll
          for (int mi = 0; mi < 4; ++mi)
            a[mi] = *(const bf16x8*)&li[(mi * 16 + arow) * 392 + kt * 32 + kseg];
#pragma unroll
          for (int ni = 0; ni < 2; ++ni) {
            acc[0][ni] = mfma16(a[0], w1r[ni][kt], acc[0][ni]);
            acc[1][ni] = mfma16(a[1], w1r[ni][kt], acc[1][ni]);
            acc[2][ni] = mfma16(a[2], w1r[ni][kt], acc[2][ni]);
            acc[3][ni] = mfma16(a[3], w1r[ni][kt], acc[3][ni]);
          }
        }
#pragma unroll
        for (int ni = 0; ni < 2; ++ni) {
          int col = wave * 32 + ni * 16 + arow;
          float bb = b1[col];
#pragma unroll
          for (int mi = 0; mi < 4; ++mi)
#pragma unroll
            for (int r = 0; r < 4; ++r)
              hh[(mi * 16 + crow + r) * 264 + col] =
                  __float2bfloat16(gelu_erf(acc[mi][ni][r] + bb));
        }
      }
      __syncthreads();

      // GEMM2: [64x256]@[256x128] -> zs += 0.3*(.+b2); 2m x 4n split, B regs
      {
        f32x4 acc[2][2];
#pragma unroll
        for (int mi = 0; mi < 2; ++mi)
#pragma unroll
          for (int ni = 0; ni < 2; ++ni) acc[mi][ni] = (f32x4){0.f, 0.f, 0.f, 0.f};
#pragma unroll
        for (int kt = 0; kt < 8; ++kt) {
          bf16x8 a0 = *(const bf16x8*)&hh[((2 * mg + 0) * 16 + arow) * 264 + kt * 32 + kseg];
          bf16x8 a1 = *(const bf16x8*)&hh[((2 * mg + 1) * 16 + arow) * 264 + kt * 32 + kseg];
#pragma unroll
          for (int ni = 0; ni < 2; ++ni) {
            acc[0][ni] = mfma16(a0, w2r[ni][kt], acc[0][ni]);
            acc[1][ni] = mfma16(a1, w2r[ni][kt], acc[1][ni]);
          }
        }
#pragma unroll
        for (int ni = 0; ni < 2; ++ni) {
          int col = (2 * ng + ni) * 16 + arow;
          float bb = b2[col];
#pragma unroll
          for (int mi = 0; mi < 2; ++mi)
#pragma unroll
            for (int r = 0; r < 4; ++r)
              zs[(2 * mg + mi) * 16 + crow + r][col] += 0.3f * (acc[mi][ni][r] + bb);
        }
      }
      __syncthreads();
    }
    ln_z();   // normalize z for gate/attn (iters 1..3 were normalized in phaseA)
    __syncthreads();

    // ================= gate + affect + QKV + attention =================
    bf16* const al  = (bf16*)scr;              // [64][136]
    bf16* const znb = (bf16*)(scr + 17408);
    bf16* const qvb = (bf16*)scr;              // alias al (dead after gate)
    bf16* const kcb = (bf16*)(scr + 34816);
    bf16* const vcb = (bf16*)(scr + 52224);

#pragma unroll
    for (int r16 = 0; r16 < 16; ++r16) {
      int r = rg4 * 16 + r16;
      float a0 = avs[r][0], a1 = avs[r][1], a2 = avs[r][2];
      al[r * 136 + c] = __float2bfloat16(
          tanhf(fmaf(a0, Wap[c], fmaf(a1, Wap[128 + c], fmaf(a2, Wap[256 + c], bap[c])))));
    }
    __syncthreads();

    {
      const int row = t >> 3, sub = t & 7;
      float s = 0.f;
      for (int j = sub; j < ND; j += 8)
        s += zs[row][j] * Wag[j] + __bfloat162float(al[row * 136 + j]) * Wag[128 + j];
#pragma unroll
      for (int o = 4; o; o >>= 1) s += __shfl_xor(s, o);
      if (sub == 0) gl[row] = sigmoidf_(s + bag[0]);
    }
    __syncthreads();
    if (t < 64) {
      float gv = gl[t];
#pragma unroll
      for (int o = 32; o; o >>= 1) gv += __shfl_xor(gv, o);
      if (t == 0) atomicAdd(gate_sum + k, gv);
    }

#pragma unroll
    for (int r16 = 0; r16 < 16; ++r16) {
      int r = rg4 * 16 + r16;
      float zv = fmaf(0.3f * gl[r], __bfloat162float(al[r * 136 + c]), zs[r][c]);
      zs[r][c] = zv;
      znb[r * 136 + c] = __float2bfloat16(zv);
    }
    __syncthreads();

    // QKV: [64x128]@[128x128] x3 ; wave w covers n-tile w
    {
      f32x4 aq[4], ak[4], av2[4];
#pragma unroll
      for (int mi = 0; mi < 4; ++mi) {
        aq[mi] = (f32x4){0.f, 0.f, 0.f, 0.f};
        ak[mi] = (f32x4){0.f, 0.f, 0.f, 0.f};
        av2[mi] = (f32x4){0.f, 0.f, 0.f, 0.f};
      }
#pragma unroll
      for (int kt = 0; kt < 4; ++kt) {
        size_t wr = (size_t)(wave * 4 + kt) * 512 + arow * 32 + kseg;
        bf16x8 bqv = *(const bf16x8*)&WqF[wr];
        bf16x8 bkv = *(const bf16x8*)&WkF[wr];
        bf16x8 bvv = *(const bf16x8*)&WvF[wr];
#pragma unroll
        for (int mi = 0; mi < 4; ++mi) {
          bf16x8 a = *(const bf16x8*)&znb[(mi * 16 + arow) * 136 + kt * 32 + kseg];
          aq[mi] = mfma16(a, bqv, aq[mi]);
          ak[mi] = mfma16(a, bkv, ak[mi]);
          av2[mi] = mfma16(a, bvv, av2[mi]);
        }
      }
      int col = wave * 16 + arow;
      float bqs = bq[col], bks = bk[col], bvs = bv[col];
#pragma unroll
      for (int mi = 0; mi < 4; ++mi)
#pragma unroll
        for (int r = 0; r < 4; ++r) {
          int row = mi * 16 + crow + r;
          qvb[row * 136 + col] = __float2bfloat16(aq[mi][r] + bqs);
          kcb[row * 136 + col] = __float2bfloat16(ak[mi][r] + bks);
          vcb[row * 136 + col] = __float2bfloat16(av2[mi][r] + bvs);
        }
    }
    __syncthreads();

    if (k < 4) {  // history writeback (slot 4 never read)
      const int c2 = (t & 63) * 2, rg8 = t >> 6;
#pragma unroll
      for (int i = 0; i < 8; ++i) {
        int r = rg8 * 8 + i;
        size_t g = row0 + r;
        unsigned uk = *(const unsigned*)&kcb[r * 136 + c2];
        unsigned uv = *(const unsigned*)&vcb[r * 136 + c2];
        __builtin_nontemporal_store(uk, (unsigned*)&kh[((size_t)k * NB + g) * ND + c2]);
        __builtin_nontemporal_store(uv, (unsigned*)&vh[((size_t)k * NB + g) * ND + c2]);
      }
    }

    if (k > 0) {
      {
        const int row = t >> 3, sub = t & 7;
        const size_t g = row0 + row;
        for (int s = 0; s <= k; ++s) {
          float p = 0.f;
          if (s == k) {
            for (int j = sub; j < ND; j += 8)
              p += __bfloat162float(qvb[row * 136 + j]) * __bfloat162float(kcb[row * 136 + j]);
          } else {
            const unsigned short* kp = (const unsigned short*)(kh + ((size_t)s * NB + g) * ND);
            for (int j = sub; j < ND; j += 8)
              p += __bfloat162float(qvb[row * 136 + j]) * bf2f(__builtin_nontemporal_load(kp + j));
          }
#pragma unroll
          for (int o = 4; o; o >>= 1) p += __shfl_xor(p, o);
          if (sub == 0) sc[row][s] = p * 0.088388347648318447f;
        }
        if (sub == 0) {
          float mx = sc[row][0];
          for (int s = 1; s <= k; ++s) mx = fmaxf(mx, sc[row][s]);
          float sum = 0.f;
          for (int s = 0; s <= k; ++s) { float e = expf(sc[row][s] - mx); sc[row][s] = e; sum += e; }
          float inv = 1.f / sum;
          for (int s = 0; s <= k; ++s) sc[row][s] *= inv;
        }
      }
      __syncthreads();

#pragma unroll
      for (int r16 = 0; r16 < 16; ++r16) {
        int r = rg4 * 16 + r16;
        size_t g = row0 + r;
        float ao = 0.f;
        for (int s = 0; s < k; ++s) {
          const unsigned short* vp = (const unsigned short*)(vh + ((size_t)s * NB + g) * ND);
          ao = fmaf(sc[r][s], bf2f(__builtin_nontemporal_load(vp + c)), ao);
        }
        ao = fmaf(sc[r][k], __bfloat162float(vcb[r * 136 + c]), ao);
        zs[r][c] += ao;
      }
      __syncthreads();
      ln_z();
    }
    __syncthreads();

    // ================= answer step =================
    bf16* const ai = (bf16*)scr;             // [64][264]
    bf16* const ha = (bf16*)(scr + 33792);   // [64][264]
    for (int r = wave; r < 64; r += 8) {
      float2 yv = *(const float2*)&ys[r][2 * lane];
      float2 zv = *(const float2*)&zs[r][2 * lane];
      float s = yv.x + yv.y + zv.x + zv.y;
      float ss = yv.x * yv.x + yv.y * yv.y + zv.x * zv.x + zv.y * zv.y;
#pragma unroll
      for (int o = 32; o; o >>= 1) { s += __shfl_xor(s, o); ss += __shfl_xor(ss, o); }
      float m = s * (1.f / 256.f);
      float rstd = rsqrtf(ss * (1.f / 256.f) - m * m + LNEPS);
      float2 w0 = *(const float2*)&lnw_ans[2 * lane];
      float2 bb0 = *(const float2*)&lnb_ans[2 * lane];
      float2 w1 = *(const float2*)&lnw_ans[128 + 2 * lane];
      float2 bb1 = *(const float2*)&lnb_ans[128 + 2 * lane];
      *(unsigned*)&ai[r * 264 + 2 * lane] =
          pk_bf2((yv.x - m) * rstd * w0.x + bb0.x, (yv.y - m) * rstd * w0.y + bb0.y);
      *(unsigned*)&ai[r * 264 + 128 + 2 * lane] =
          pk_bf2((zv.x - m) * rstd * w1.x + bb1.x, (zv.y - m) * rstd * w1.y + bb1.y);
    }
    __syncthreads();

    // ans GEMM1: [64x256]@[256x256] -> ha
    {
      f32x4 acc[4][2];
#pragma unroll
      for (int mi = 0; mi < 4; ++mi)
#pragma unroll
        for (int ni = 0; ni < 2; ++ni) acc[mi][ni] = (f32x4){0.f, 0.f, 0.f, 0.f};
#pragma unroll
      for (int kt = 0; kt < 8; ++kt) {
        bf16x8 a[4];
#pragma unroll
        for (int mi = 0; mi < 4; ++mi)
          a[mi] = *(const bf16x8*)&ai[(mi * 16 + arow) * 264 + kt * 32 + kseg];
#pragma unroll
        for (int ni = 0; ni < 2; ++ni) {
          bf16x8 b = *(const bf16x8*)&WA1F[(size_t)((wave * 2 + ni) * 8 + kt) * 512 +
                                           arow * 32 + kseg];
          acc[0][ni] = mfma16(a[0], b, acc[0][ni]);
          acc[1][ni] = mfma16(a[1], b, acc[1][ni]);
          acc[2][ni] = mfma16(a[2], b, acc[2][ni]);
          acc[3][ni] = mfma16(a[3], b, acc[3][ni]);
        }
      }
#pragma unroll
      for (int ni = 0; ni < 2; ++ni) {
        int col = wave * 32 + ni * 16 + arow;
        float bb = ba1[col];
#pragma unroll
        for (int mi = 0; mi < 4; ++mi)
#pragma unroll
          for (int r = 0; r < 4; ++r)
            ha[(mi * 16 + crow + r) * 264 + col] =
                __float2bfloat16(gelu_erf(acc[mi][ni][r] + bb));
      }
    }
    __syncthreads();

    // ans GEMM2: [64x256]@[256x128] -> ys += 0.4*(.+ba2)
    {
      f32x4 acc[4];
#pragma unroll
      for (int mi = 0; mi < 4; ++mi) acc[mi] = (f32x4){0.f, 0.f, 0.f, 0.f};
#pragma unroll
      for (int kt = 0; kt < 8; ++kt) {
        bf16x8 b = *(const bf16x8*)&WA2F[(size_t)(wave * 8 + kt) * 512 + arow * 32 + kseg];
#pragma unroll
        for (int mi = 0; mi < 4; ++mi) {
          bf16x8 a = *(const bf16x8*)&ha[(mi * 16 + arow) * 264 + kt * 32 + kseg];
          acc[mi] = mfma16(a, b, acc[mi]);
        }
      }
      int col = wave * 16 + arow;
      float bb = ba2[col];
#pragma unroll
      for (int mi = 0; mi < 4; ++mi)
#pragma unroll
        for (int r = 0; r < 4; ++r)
          ys[mi * 16 + crow + r][col] += 0.4f * (acc[mi][r] + bb);
    }
    __syncthreads();
  }  // k loop

  // ================= PAD head + y writeback =================
  float* const h1 = (float*)scr;  // [64][68]
  {
    const int cc = t & 63, rg8 = t >> 6;
    float acc[8];
#pragma unroll
    for (int r = 0; r < 8; ++r) acc[r] = 0.f;
    for (int j0 = 0; j0 < ND; j0 += 4) {
      float w0 = Wp1[(j0 + 0) * 64 + cc], w1 = Wp1[(j0 + 1) * 64 + cc];
      float w2 = Wp1[(j0 + 2) * 64 + cc], w3 = Wp1[(j0 + 3) * 64 + cc];
#pragma unroll
      for (int r = 0; r < 8; ++r) {
        float4 a = *reinterpret_cast<const float4*>(&zs[rg8 * 8 + r][j0]);
        acc[r] = fmaf(a.x, w0, fmaf(a.y, w1, fmaf(a.z, w2, fmaf(a.w, w3, acc[r]))));
      }
    }
    float bb = bp1[cc];
#pragma unroll
    for (int r = 0; r < 8; ++r) h1[(rg8 * 8 + r) * 68 + cc] = gelu_erf(acc[r] + bb);
  }
  __syncthreads();
  {
    const int row = t >> 3, sub = t & 7;
    if (sub < 3) {
      float p = 0.f;
      for (int j = 0; j < 64; ++j) p += h1[row * 68 + j] * Wp2[j * 3 + sub];
      pad_out[(size_t)(row0 + row) * 3 + sub] = tanhf(p + bp2[sub]);
    }
  }
#pragma unroll
  for (int r16 = 0; r16 < 16; ++r16) {
    int r = rg4 * 16 + r16;
    y_out[(size_t)(row0 + r) * ND + c] = ys[r][c];
  }
}

__global__ void finalize_confs(const float* __restrict__ gs, float* __restrict__ confs) {
  int i = threadIdx.x;
  if (i < 5) confs[i] = gs[i] * (1.0f / 32768.0f);
}

// ------------------------------------------------------------------- launch
extern "C" void kernel_launch(void* const* d_in, const int* in_sizes, int n_in,
                              void* d_out, int out_size, void* d_ws, size_t ws_size,
                              hipStream_t stream) {
  const float* x       = (const float*)d_in[0];
  const float* y_init  = (const float*)d_in[1];
  const float* av      = (const float*)d_in[2];
  const float* ln_lat_w = (const float*)d_in[3];
  const float* ln_lat_b = (const float*)d_in[4];
  const float* ln_ans_w = (const float*)d_in[5];
  const float* ln_ans_b = (const float*)d_in[6];
  const float* ln_z_w   = (const float*)d_in[7];
  const float* ln_z_b   = (const float*)d_in[8];
  const float* W_lat1 = (const float*)d_in[9];  const float* b_lat1 = (const float*)d_in[10];
  const float* W_lat2 = (const float*)d_in[11]; const float* b_lat2 = (const float*)d_in[12];
  const float* W_ans1 = (const float*)d_in[13]; const float* b_ans1 = (const float*)d_in[14];
  const float* W_ans2 = (const float*)d_in[15]; const float* b_ans2 = (const float*)d_in[16];
  const float* W_ap = (const float*)d_in[17];   const float* b_ap = (const float*)d_in[18];
  const float* W_ag = (const float*)d_in[19];   const float* b_ag = (const float*)d_in[20];
  const float* Wq = (const float*)d_in[21];     const float* bq = (const float*)d_in[22];
  const float* Wk = (const float*)d_in[23];     const float* bk = (const float*)d_in[24];
  const float* Wv = (const float*)d_in[25];     const float* bv = (const float*)d_in[26];
  const float* W_p1 = (const float*)d_in[27];   const float* b_p1 = (const float*)d_in[28];
  const float* W_p2 = (const float*)d_in[29];   const float* b_p2 = (const float*)d_in[30];

  float* y     = (float*)d_out;
  float* confs = (float*)d_out + (size_t)NB * ND;
  float* pad   = confs + 5;

  char* p = (char*)d_ws;
  float* gate_sum = (float*)p;
  bf16* kh   = (bf16*)(p + 256);
  bf16* vh   = kh + (size_t)4 * NB * ND;
  bf16* W1F  = vh + (size_t)4 * NB * ND;
  bf16* W2F  = W1F + 384 * 256;
  bf16* WA1F = W2F + 256 * 128;
  bf16* WA2F = WA1F + 256 * 256;
  bf16* WqF  = WA2F + 256 * 128;
  bf16* WkF  = WqF + 128 * 128;
  bf16* WvF  = WkF + 128 * 128;

  hipMemsetAsync(gate_sum, 0, 32, stream);
  prep_w_frag<<<(384 * 256 + 255) / 256, 256, 0, stream>>>(W_lat1, W1F, 384, 256);
  prep_w_frag<<<(256 * 128 + 255) / 256, 256, 0, stream>>>(W_lat2, W2F, 256, 128);
  prep_w_frag<<<(256 * 256 + 255) / 256, 256, 0, stream>>>(W_ans1, WA1F, 256, 256);
  prep_w_frag<<<(256 * 128 + 255) / 256, 256, 0, stream>>>(W_ans2, WA2F, 256, 128);
  prep_w_frag<<<(128 * 128 + 255) / 256, 256, 0, stream>>>(Wq, WqF, 128, 128);
  prep_w_frag<<<(128 * 128 + 255) / 256, 256, 0, stream>>>(Wk, WkF, 128, 128);
  prep_w_frag<<<(128 * 128 + 255) / 256, 256, 0, stream>>>(Wv, WvF, 128, 128);

  trm_fused<<<NB / 64, 512, 0, stream>>>(
      x, y_init, av,
      ln_lat_w, ln_lat_b, ln_ans_w, ln_ans_b, ln_z_w, ln_z_b,
      W1F, b_lat1, W2F, b_lat2, WA1F, b_ans1, WA2F, b_ans2,
      W_ap, b_ap, W_ag, b_ag,
      WqF, bq, WkF, bk, WvF, bv,
      W_p1, b_p1, W_p2, b_p2,
      y, pad, gate_sum, kh, vh);

  finalize_confs<<<1, 64, 0, stream>>>(gate_sum, confs);
}

// Round 6
// 1659.340 us; speedup vs baseline: 1.2902x; 1.2902x over previous
//
#include <hip/hip_runtime.h>
#include <hip/hip_bf16.h>
#include <math.h>

// TinyRecursiveModelTRMv3 — Round 6: moderate fusion, spill-free.
//   per outer step k: latent4 (all 4 inner iters, z/x/y LDS-resident)
//                     step_tail (gate+affect+QKV+attn+LN+answer)
//   + pad_head + finalize. 32 rows/block, 256 thr, 2 blocks/CU.
// ws: [0,256) gate sums | z f32[B][128] | kh bf16[4][B][128] | vh ... | weights frag-major

constexpr int NB = 32768;
constexpr int ND = 128;
constexpr float LNEPS = 1e-5f;

typedef short bf16x8 __attribute__((ext_vector_type(8)));
typedef float f32x4 __attribute__((ext_vector_type(4)));
using bf16 = __hip_bfloat16;

static __device__ __forceinline__ float gelu_erf(float x) {
  return 0.5f * x * (1.0f + erff(x * 0.70710678118654752440f));
}
static __device__ __forceinline__ float sigmoidf_(float x) {
  return 1.0f / (1.0f + expf(-x));
}
static __device__ __forceinline__ f32x4 mfma16(bf16x8 a, bf16x8 b, f32x4 c) {
  return __builtin_amdgcn_mfma_f32_16x16x32_bf16(a, b, c, 0, 0, 0);
}
static __device__ __forceinline__ float bf2f(unsigned u) {  // low 16 bits = bf16
  unsigned v = u << 16;
  return __builtin_bit_cast(float, v);
}
static __device__ __forceinline__ unsigned pk_bf2(float a, float b) {
  unsigned ua = __builtin_bit_cast(unsigned, a);
  unsigned ub = __builtin_bit_cast(unsigned, b);
  ua = (ua + 0x7fffu + ((ua >> 16) & 1u)) >> 16;
  ub = (ub + 0x7fffu + ((ub >> 16) & 1u)) & 0xffff0000u;
  return ub | ua;
}

// fragment-major: f = ((n>>4)*(K>>5) + (k>>5))*512 + (n&15)*32 + (k&31)
__global__ void prep_w_frag(const float* __restrict__ src, bf16* __restrict__ dst,
                            int K, int N) {
  int i = blockIdx.x * 256 + threadIdx.x;
  if (i >= K * N) return;
  int k = i / N, n = i - k * N;
  int f = ((n >> 4) * (K >> 5) + (k >> 5)) * 512 + (n & 15) * 32 + (k & 31);
  dst[f] = __float2bfloat16(src[i]);
}

// ---------------------------------------------------------------- latent4
// 4 inner iterations: z <- LN(z + 0.3*(gelu(LN([x,y,z])@W1+b1)@W2+b2))
__global__ __launch_bounds__(256) void latent4(
    const float* __restrict__ x, const float* __restrict__ y,
    float* __restrict__ z,
    const float* __restrict__ lnw, const float* __restrict__ lnb,   // [384]
    const bf16* __restrict__ W1F, const float* __restrict__ b1,     // K=384,N=256
    const bf16* __restrict__ W2F, const float* __restrict__ b2,     // K=256,N=128
    const float* __restrict__ lzw, const float* __restrict__ lzb)
{
  __shared__ __align__(16) char pool[76288];
  float (* const zs)[132] = (float(*)[132])pool;        // 16896
  bf16* const xb = (bf16*)(pool + 16896);               // [32][136]
  bf16* const yb = (bf16*)(pool + 25600);               // [32][136]
  bf16* const li = (bf16*)(pool + 34304);               // [32][392]
  bf16* const hh = (bf16*)(pool + 59392);               // [32][264]

  const int t = threadIdx.x;
  const int wave = t >> 6, lane = t & 63;
  const int c = t & 127, rg = t >> 7;
  const int row0 = blockIdx.x * 32;
  const int arow = lane & 15;
  const int kseg = (lane >> 4) * 8;
  const int crow = (lane >> 4) * 4;

  // init: x,y -> bf16 LDS ; z -> f32 LDS
#pragma unroll
  for (int r16 = 0; r16 < 16; ++r16) {
    int r = rg * 16 + r16;
    size_t g = row0 + r;
    xb[r * 136 + c] = __float2bfloat16(x[g * ND + c]);
    yb[r * 136 + c] = __float2bfloat16(y[g * ND + c]);
    zs[r][c] = z[g * ND + c];
  }
  __syncthreads();

  for (int n = 0; n < 4; ++n) {
    // LN over [x|y|z] (384) -> li bf16
    for (int r = wave; r < 32; r += 4) {
      unsigned ux = *(const unsigned*)&xb[r * 136 + 2 * lane];
      unsigned uy = *(const unsigned*)&yb[r * 136 + 2 * lane];
      float2 zv = *(const float2*)&zs[r][2 * lane];
      float x0 = bf2f(ux & 0xffffu), x1 = bf2f(ux >> 16);
      float y0 = bf2f(uy & 0xffffu), y1 = bf2f(uy >> 16);
      float s = x0 + x1 + y0 + y1 + zv.x + zv.y;
      float ss = x0 * x0 + x1 * x1 + y0 * y0 + y1 * y1 + zv.x * zv.x + zv.y * zv.y;
#pragma unroll
      for (int o = 32; o; o >>= 1) { s += __shfl_xor(s, o); ss += __shfl_xor(ss, o); }
      float m = s * (1.f / 384.f);
      float rstd = rsqrtf(ss * (1.f / 384.f) - m * m + LNEPS);
      float2 w0 = *(const float2*)&lnw[2 * lane];
      float2 c0 = *(const float2*)&lnb[2 * lane];
      float2 w1 = *(const float2*)&lnw[128 + 2 * lane];
      float2 c1 = *(const float2*)&lnb[128 + 2 * lane];
      float2 w2 = *(const float2*)&lnw[256 + 2 * lane];
      float2 c2 = *(const float2*)&lnb[256 + 2 * lane];
      *(unsigned*)&li[r * 392 + 2 * lane] =
          pk_bf2((x0 - m) * rstd * w0.x + c0.x, (x1 - m) * rstd * w0.y + c0.y);
      *(unsigned*)&li[r * 392 + 128 + 2 * lane] =
          pk_bf2((y0 - m) * rstd * w1.x + c1.x, (y1 - m) * rstd * w1.y + c1.y);
      *(unsigned*)&li[r * 392 + 256 + 2 * lane] =
          pk_bf2((zv.x - m) * rstd * w2.x + c2.x, (zv.y - m) * rstd * w2.y + c2.y);
    }
    __syncthreads();

    // GEMM1: [32x384]@[384x256] -> hh = gelu(.+b1); wave covers n-tiles 4w..4w+3
    {
      f32x4 acc[2][4];
#pragma unroll
      for (int mi = 0; mi < 2; ++mi)
#pragma unroll
        for (int ni = 0; ni < 4; ++ni) acc[mi][ni] = (f32x4){0.f, 0.f, 0.f, 0.f};
#pragma unroll
      for (int kt = 0; kt < 12; ++kt) {
        bf16x8 a0 = *(const bf16x8*)&li[arow * 392 + kt * 32 + kseg];
        bf16x8 a1 = *(const bf16x8*)&li[(16 + arow) * 392 + kt * 32 + kseg];
#pragma unroll
        for (int ni = 0; ni < 4; ++ni) {
          bf16x8 b = *(const bf16x8*)&W1F[(size_t)((wave * 4 + ni) * 12 + kt) * 512 +
                                          arow * 32 + kseg];
          acc[0][ni] = mfma16(a0, b, acc[0][ni]);
          acc[1][ni] = mfma16(a1, b, acc[1][ni]);
        }
      }
#pragma unroll
      for (int ni = 0; ni < 4; ++ni) {
        int col = (wave * 4 + ni) * 16 + arow;
        float bb = b1[col];
#pragma unroll
        for (int mi = 0; mi < 2; ++mi)
#pragma unroll
          for (int r = 0; r < 4; ++r)
            hh[(mi * 16 + crow + r) * 264 + col] =
                __float2bfloat16(gelu_erf(acc[mi][ni][r] + bb));
      }
    }
    __syncthreads();

    // GEMM2: [32x256]@[256x128] -> zs += 0.3*(.+b2); wave covers n-tiles 2w..2w+1
    {
      f32x4 acc[2][2];
#pragma unroll
      for (int mi = 0; mi < 2; ++mi)
#pragma unroll
        for (int ni = 0; ni < 2; ++ni) acc[mi][ni] = (f32x4){0.f, 0.f, 0.f, 0.f};
#pragma unroll
      for (int kt = 0; kt < 8; ++kt) {
        bf16x8 a0 = *(const bf16x8*)&hh[arow * 264 + kt * 32 + kseg];
        bf16x8 a1 = *(const bf16x8*)&hh[(16 + arow) * 264 + kt * 32 + kseg];
#pragma unroll
        for (int ni = 0; ni < 2; ++ni) {
          bf16x8 b = *(const bf16x8*)&W2F[(size_t)((wave * 2 + ni) * 8 + kt) * 512 +
                                          arow * 32 + kseg];
          acc[0][ni] = mfma16(a0, b, acc[0][ni]);
          acc[1][ni] = mfma16(a1, b, acc[1][ni]);
        }
      }
#pragma unroll
      for (int ni = 0; ni < 2; ++ni) {
        int col = (wave * 2 + ni) * 16 + arow;
        float bb = b2[col];
#pragma unroll
        for (int mi = 0; mi < 2; ++mi)
#pragma unroll
          for (int r = 0; r < 4; ++r)
            zs[mi * 16 + crow + r][col] += 0.3f * (acc[mi][ni][r] + bb);
      }
    }
    __syncthreads();

    // z = LN(z)
    for (int r = wave; r < 32; r += 4) {
      float2 v = *(const float2*)&zs[r][2 * lane];
      float s = v.x + v.y, ss = v.x * v.x + v.y * v.y;
#pragma unroll
      for (int o = 32; o; o >>= 1) { s += __shfl_xor(s, o); ss += __shfl_xor(ss, o); }
      float m = s * (1.f / 128.f);
      float rstd = rsqrtf(ss * (1.f / 128.f) - m * m + LNEPS);
      float2 w = *(const float2*)&lzw[2 * lane];
      float2 b = *(const float2*)&lzb[2 * lane];
      float2 o2;
      o2.x = (v.x - m) * rstd * w.x + b.x;
      o2.y = (v.y - m) * rstd * w.y + b.y;
      *(float2*)&zs[r][2 * lane] = o2;
    }
    __syncthreads();
  }

  // write back z
#pragma unroll
  for (int r16 = 0; r16 < 16; ++r16) {
    int r = rg * 16 + r16;
    z[(size_t)(row0 + r) * ND + c] = zs[r][c];
  }
}

// ---------------------------------------------------------------- step_tail
// gate + affect + QKV + attention + LN, then answer MLP (y += ...)
__global__ __launch_bounds__(256) void step_tail(
    float* __restrict__ y, float* __restrict__ z,
    const float* __restrict__ av_g,
    const float* __restrict__ lnw_ans, const float* __restrict__ lnb_ans,
    const float* __restrict__ lzw, const float* __restrict__ lzb,
    const bf16* __restrict__ WA1F, const float* __restrict__ ba1,
    const bf16* __restrict__ WA2F, const float* __restrict__ ba2,
    const float* __restrict__ Wap, const float* __restrict__ bap,
    const float* __restrict__ Wag, const float* __restrict__ bag,
    const bf16* __restrict__ WqF, const float* __restrict__ bq,
    const bf16* __restrict__ WkF, const float* __restrict__ bk,
    const bf16* __restrict__ WvF, const float* __restrict__ bv,
    float* __restrict__ gate_sum,
    bf16* __restrict__ kh, bf16* __restrict__ vh, int k)
{
  __shared__ __align__(16) char pool[77312];
  __shared__ float sc[32][8];
  __shared__ float gl[32];
  __shared__ float avs[32][3];

  float (* const zs)[132] = (float(*)[132])pool;        // 16896
  float (* const ys)[132] = (float(*)[132])(pool + 16896);
  char* const scr = pool + 33792;                       // 43520 bytes
  bf16* const al  = (bf16*)scr;                         // [32][136]
  bf16* const znb = (bf16*)(scr + 8704);
  bf16* const qvb = (bf16*)(scr + 17408);
  bf16* const kcb = (bf16*)(scr + 26112);
  bf16* const vcb = (bf16*)(scr + 34816);
  bf16* const ai = (bf16*)scr;                          // [32][264] (answer phase)
  bf16* const ha = (bf16*)(scr + 16896);                // [32][264]

  const int t = threadIdx.x;
  const int wave = t >> 6, lane = t & 63;
  const int c = t & 127, rg = t >> 7;
  const int row0 = blockIdx.x * 32;
  const int arow = lane & 15;
  const int kseg = (lane >> 4) * 8;
  const int crow = (lane >> 4) * 4;

  // load z, y, av
#pragma unroll
  for (int r16 = 0; r16 < 16; ++r16) {
    int r = rg * 16 + r16;
    size_t g = row0 + r;
    zs[r][c] = z[g * ND + c];
    ys[r][c] = y[g * ND + c];
  }
  if (t < 96) ((float*)avs)[t] = av_g[(size_t)row0 * 3 + t];
  __syncthreads();

  // affect latent
#pragma unroll
  for (int r16 = 0; r16 < 16; ++r16) {
    int r = rg * 16 + r16;
    float a0 = avs[r][0], a1 = avs[r][1], a2 = avs[r][2];
    al[r * 136 + c] = __float2bfloat16(
        tanhf(fmaf(a0, Wap[c], fmaf(a1, Wap[128 + c], fmaf(a2, Wap[256 + c], bap[c])))));
  }
  __syncthreads();

  // gate
  {
    const int row = t >> 3, sub = t & 7;
    float s = 0.f;
    for (int j = sub; j < ND; j += 8)
      s += zs[row][j] * Wag[j] + __bfloat162float(((bf16*)al)[row * 136 + j]) * Wag[128 + j];
#pragma unroll
    for (int o = 4; o; o >>= 1) s += __shfl_xor(s, o);
    if (sub == 0) gl[row] = sigmoidf_(s + bag[0]);
  }
  __syncthreads();
  if (t < 64) {
    float gv = (t < 32) ? gl[t] : 0.f;
#pragma unroll
    for (int o = 32; o; o >>= 1) gv += __shfl_xor(gv, o);
    if (t == 0) atomicAdd(gate_sum + k, gv);
  }

  // zn = z + 0.3*g*al (in place) + bf16 copy
#pragma unroll
  for (int r16 = 0; r16 < 16; ++r16) {
    int r = rg * 16 + r16;
    float zv = fmaf(0.3f * gl[r], __bfloat162float(al[r * 136 + c]), zs[r][c]);
    zs[r][c] = zv;
    znb[r * 136 + c] = __float2bfloat16(zv);
  }
  __syncthreads();

  // QKV MFMA: wave covers n-tiles 2w..2w+1 of each of q,k,v
  {
    f32x4 aq[2][2], ak[2][2], av2[2][2];
#pragma unroll
    for (int mi = 0; mi < 2; ++mi)
#pragma unroll
      for (int ni = 0; ni < 2; ++ni) {
        aq[mi][ni] = (f32x4){0.f, 0.f, 0.f, 0.f};
        ak[mi][ni] = (f32x4){0.f, 0.f, 0.f, 0.f};
        av2[mi][ni] = (f32x4){0.f, 0.f, 0.f, 0.f};
      }
#pragma unroll
    for (int kt = 0; kt < 4; ++kt) {
      bf16x8 a0 = *(const bf16x8*)&znb[arow * 136 + kt * 32 + kseg];
      bf16x8 a1 = *(const bf16x8*)&znb[(16 + arow) * 136 + kt * 32 + kseg];
#pragma unroll
      for (int ni = 0; ni < 2; ++ni) {
        size_t wr = (size_t)((wave * 2 + ni) * 4 + kt) * 512 + arow * 32 + kseg;
        bf16x8 bqv = *(const bf16x8*)&WqF[wr];
        bf16x8 bkv = *(const bf16x8*)&WkF[wr];
        bf16x8 bvv = *(const bf16x8*)&WvF[wr];
        aq[0][ni] = mfma16(a0, bqv, aq[0][ni]);   aq[1][ni] = mfma16(a1, bqv, aq[1][ni]);
        ak[0][ni] = mfma16(a0, bkv, ak[0][ni]);   ak[1][ni] = mfma16(a1, bkv, ak[1][ni]);
        av2[0][ni] = mfma16(a0, bvv, av2[0][ni]); av2[1][ni] = mfma16(a1, bvv, av2[1][ni]);
      }
    }
#pragma unroll
    for (int ni = 0; ni < 2; ++ni) {
      int col = (wave * 2 + ni) * 16 + arow;
      float bqs = bq[col], bks = bk[col], bvs = bv[col];
#pragma unroll
      for (int mi = 0; mi < 2; ++mi)
#pragma unroll
        for (int r = 0; r < 4; ++r) {
          int row = mi * 16 + crow + r;
          qvb[row * 136 + col] = __float2bfloat16(aq[mi][ni][r] + bqs);
          kcb[row * 136 + col] = __float2bfloat16(ak[mi][ni][r] + bks);
          vcb[row * 136 + col] = __float2bfloat16(av2[mi][ni][r] + bvs);
        }
    }
  }
  __syncthreads();

  // history writeback (slot 4 never read)
  if (k < 4) {
    const int c2 = (t & 63) * 2, rg8 = t >> 6;
#pragma unroll
    for (int i = 0; i < 8; ++i) {
      int r = rg8 * 8 + i;
      size_t g = row0 + r;
      unsigned uk = *(const unsigned*)&kcb[r * 136 + c2];
      unsigned uv = *(const unsigned*)&vcb[r * 136 + c2];
      __builtin_nontemporal_store(uk, (unsigned*)&kh[((size_t)k * NB + g) * ND + c2]);
      __builtin_nontemporal_store(uv, (unsigned*)&vh[((size_t)k * NB + g) * ND + c2]);
    }
  }

  if (k > 0) {
    // scores + softmax
    {
      const int row = t >> 3, sub = t & 7;
      const size_t g = row0 + row;
      for (int s = 0; s <= k; ++s) {
        float p = 0.f;
        if (s == k) {
          for (int j = sub; j < ND; j += 8)
            p += __bfloat162float(qvb[row * 136 + j]) * __bfloat162float(kcb[row * 136 + j]);
        } else {
          const unsigned short* kp = (const unsigned short*)(kh + ((size_t)s * NB + g) * ND);
          for (int j = sub; j < ND; j += 8)
            p += __bfloat162float(qvb[row * 136 + j]) *
                 bf2f((unsigned)__builtin_nontemporal_load(kp + j));
        }
#pragma unroll
        for (int o = 4; o; o >>= 1) p += __shfl_xor(p, o);
        if (sub == 0) sc[row][s] = p * 0.088388347648318447f;
      }
      if (sub == 0) {
        float mx = sc[row][0];
        for (int s = 1; s <= k; ++s) mx = fmaxf(mx, sc[row][s]);
        float sum = 0.f;
        for (int s = 0; s <= k; ++s) { float e = expf(sc[row][s] - mx); sc[row][s] = e; sum += e; }
        float inv = 1.f / sum;
        for (int s = 0; s <= k; ++s) sc[row][s] *= inv;
      }
    }
    __syncthreads();

    // attn_out + residual
#pragma unroll
    for (int r16 = 0; r16 < 16; ++r16) {
      int r = rg * 16 + r16;
      size_t g = row0 + r;
      float ao = 0.f;
      for (int s = 0; s < k; ++s) {
        const unsigned short* vp = (const unsigned short*)(vh + ((size_t)s * NB + g) * ND);
        ao = fmaf(sc[r][s], bf2f((unsigned)__builtin_nontemporal_load(vp + c)), ao);
      }
      ao = fmaf(sc[r][k], __bfloat162float(vcb[r * 136 + c]), ao);
      zs[r][c] += ao;
    }
    __syncthreads();

    // z = LN(z)
    for (int r = wave; r < 32; r += 4) {
      float2 v = *(const float2*)&zs[r][2 * lane];
      float s = v.x + v.y, ss = v.x * v.x + v.y * v.y;
#pragma unroll
      for (int o = 32; o; o >>= 1) { s += __shfl_xor(s, o); ss += __shfl_xor(ss, o); }
      float m = s * (1.f / 128.f);
      float rstd = rsqrtf(ss * (1.f / 128.f) - m * m + LNEPS);
      float2 w = *(const float2*)&lzw[2 * lane];
      float2 b = *(const float2*)&lzb[2 * lane];
      float2 o2;
      o2.x = (v.x - m) * rstd * w.x + b.x;
      o2.y = (v.y - m) * rstd * w.y + b.y;
      *(float2*)&zs[r][2 * lane] = o2;
    }
  }
  __syncthreads();

  // write z back (input of next latent4 / pad_head)
#pragma unroll
  for (int r16 = 0; r16 < 16; ++r16) {
    int r = rg * 16 + r16;
    z[(size_t)(row0 + r) * ND + c] = zs[r][c];
  }

  // ---- answer step ----
  for (int r = wave; r < 32; r += 4) {
    float2 yv = *(const float2*)&ys[r][2 * lane];
    float2 zv = *(const float2*)&zs[r][2 * lane];
    float s = yv.x + yv.y + zv.x + zv.y;
    float ss = yv.x * yv.x + yv.y * yv.y + zv.x * zv.x + zv.y * zv.y;
#pragma unroll
    for (int o = 32; o; o >>= 1) { s += __shfl_xor(s, o); ss += __shfl_xor(ss, o); }
    float m = s * (1.f / 256.f);
    float rstd = rsqrtf(ss * (1.f / 256.f) - m * m + LNEPS);
    float2 w0 = *(const float2*)&lnw_ans[2 * lane];
    float2 c0 = *(const float2*)&lnb_ans[2 * lane];
    float2 w1 = *(const float2*)&lnw_ans[128 + 2 * lane];
    float2 c1 = *(const float2*)&lnb_ans[128 + 2 * lane];
    *(unsigned*)&ai[r * 264 + 2 * lane] =
        pk_bf2((yv.x - m) * rstd * w0.x + c0.x, (yv.y - m) * rstd * w0.y + c0.y);
    *(unsigned*)&ai[r * 264 + 128 + 2 * lane] =
        pk_bf2((zv.x - m) * rstd * w1.x + c1.x, (zv.y - m) * rstd * w1.y + c1.y);
  }
  __syncthreads();

  // ans GEMM1: [32x256]@[256x256] -> ha
  {
    f32x4 acc[2][4];
#pragma unroll
    for (int mi = 0; mi < 2; ++mi)
#pragma unroll
      for (int ni = 0; ni < 4; ++ni) acc[mi][ni] = (f32x4){0.f, 0.f, 0.f, 0.f};
#pragma unroll
    for (int kt = 0; kt < 8; ++kt) {
      bf16x8 a0 = *(const bf16x8*)&ai[arow * 264 + kt * 32 + kseg];
      bf16x8 a1 = *(const bf16x8*)&ai[(16 + arow) * 264 + kt * 32 + kseg];
#pragma unroll
      for (int ni = 0; ni < 4; ++ni) {
        bf16x8 b = *(const bf16x8*)&WA1F[(size_t)((wave * 4 + ni) * 8 + kt) * 512 +
                                         arow * 32 + kseg];
        acc[0][ni] = mfma16(a0, b, acc[0][ni]);
        acc[1][ni] = mfma16(a1, b, acc[1][ni]);
      }
    }
#pragma unroll
    for (int ni = 0; ni < 4; ++ni) {
      int col = (wave * 4 + ni) * 16 + arow;
      float bb = ba1[col];
#pragma unroll
      for (int mi = 0; mi < 2; ++mi)
#pragma unroll
        for (int r = 0; r < 4; ++r)
          ha[(mi * 16 + crow + r) * 264 + col] =
              __float2bfloat16(gelu_erf(acc[mi][ni][r] + bb));
    }
  }
  __syncthreads();

  // ans GEMM2: [32x256]@[256x128] -> ys += 0.4*(.+ba2)
  {
    f32x4 acc[2][2];
#pragma unroll
    for (int mi = 0; mi < 2; ++mi)
#pragma unroll
      for (int ni = 0; ni < 2; ++ni) acc[mi][ni] = (f32x4){0.f, 0.f, 0.f, 0.f};
#pragma unroll
    for (int kt = 0; kt < 8; ++kt) {
      bf16x8 a0 = *(const bf16x8*)&ha[arow * 264 + kt * 32 + kseg];
      bf16x8 a1 = *(const bf16x8*)&ha[(16 + arow) * 264 + kt * 32 + kseg];
#pragma unroll
      for (int ni = 0; ni < 2; ++ni) {
        bf16x8 b = *(const bf16x8*)&WA2F[(size_t)((wave * 2 + ni) * 8 + kt) * 512 +
                                         arow * 32 + kseg];
        acc[0][ni] = mfma16(a0, b, acc[0][ni]);
        acc[1][ni] = mfma16(a1, b, acc[1][ni]);
      }
    }
#pragma unroll
    for (int ni = 0; ni < 2; ++ni) {
      int col = (wave * 2 + ni) * 16 + arow;
      float bb = ba2[col];
#pragma unroll
      for (int mi = 0; mi < 2; ++mi)
#pragma unroll
        for (int r = 0; r < 4; ++r)
          ys[mi * 16 + crow + r][col] += 0.4f * (acc[mi][ni][r] + bb);
    }
  }
  __syncthreads();

  // write y back
#pragma unroll
  for (int r16 = 0; r16 < 16; ++r16) {
    int r = rg * 16 + r16;
    y[(size_t)(row0 + r) * ND + c] = ys[r][c];
  }
}

// ------------------------------------------------------------------ PAD head
__global__ __launch_bounds__(256) void pad_head(
    const float* __restrict__ z,
    const float* __restrict__ W1, const float* __restrict__ b1,
    const float* __restrict__ W2, const float* __restrict__ b2,
    float* __restrict__ out)
{
  __shared__ __align__(16) float zsm[32][132];
  __shared__ __align__(16) float h[32][68];
  const int t = threadIdx.x;
  const int row0 = blockIdx.x * 32;
  {
    const int c = t & 127, rg = t >> 7;
#pragma unroll
    for (int r16 = 0; r16 < 16; ++r16) {
      int r = rg * 16 + r16;
      zsm[r][c] = z[(size_t)(row0 + r) * ND + c];
    }
  }
  __syncthreads();
  {
    const int c = t & 63, rg8 = t >> 6;
    float acc[8];
#pragma unroll
    for (int r = 0; r < 8; ++r) acc[r] = 0.f;
    for (int j0 = 0; j0 < ND; j0 += 4) {
      float w0 = W1[(j0 + 0) * 64 + c], w1 = W1[(j0 + 1) * 64 + c];
      float w2 = W1[(j0 + 2) * 64 + c], w3 = W1[(j0 + 3) * 64 + c];
#pragma unroll
      for (int r = 0; r < 8; ++r) {
        float4 a = *reinterpret_cast<const float4*>(&zsm[rg8 * 8 + r][j0]);
        acc[r] = fmaf(a.x, w0, fmaf(a.y, w1, fmaf(a.z, w2, fmaf(a.w, w3, acc[r]))));
      }
    }
    float bb = b1[c];
#pragma unroll
    for (int r = 0; r < 8; ++r) h[rg8 * 8 + r][c] = gelu_erf(acc[r] + bb);
  }
  __syncthreads();
  {
    const int row = t >> 3, sub = t & 7;
    if (sub < 3) {
      float p = 0.f;
      for (int j = 0; j < 64; ++j) p += h[row][j] * W2[j * 3 + sub];
      out[(size_t)(row0 + row) * 3 + sub] = tanhf(p + b2[sub]);
    }
  }
}

__global__ void finalize_confs(const float* __restrict__ gs, float* __restrict__ confs) {
  int i = threadIdx.x;
  if (i < 5) confs[i] = gs[i] * (1.0f / 32768.0f);
}

// ------------------------------------------------------------------- launch
extern "C" void kernel_launch(void* const* d_in, const int* in_sizes, int n_in,
                              void* d_out, int out_size, void* d_ws, size_t ws_size,
                              hipStream_t stream) {
  const float* x       = (const float*)d_in[0];
  const float* y_init  = (const float*)d_in[1];
  const float* av      = (const float*)d_in[2];
  const float* ln_lat_w = (const float*)d_in[3];
  const float* ln_lat_b = (const float*)d_in[4];
  const float* ln_ans_w = (const float*)d_in[5];
  const float* ln_ans_b = (const float*)d_in[6];
  const float* ln_z_w   = (const float*)d_in[7];
  const float* ln_z_b   = (const float*)d_in[8];
  const float* W_lat1 = (const float*)d_in[9];  const float* b_lat1 = (const float*)d_in[10];
  const float* W_lat2 = (const float*)d_in[11]; const float* b_lat2 = (const float*)d_in[12];
  const float* W_ans1 = (const float*)d_in[13]; const float* b_ans1 = (const float*)d_in[14];
  const float* W_ans2 = (const float*)d_in[15]; const float* b_ans2 = (const float*)d_in[16];
  const float* W_ap = (const float*)d_in[17];   const float* b_ap = (const float*)d_in[18];
  const float* W_ag = (const float*)d_in[19];   const float* b_ag = (const float*)d_in[20];
  const float* Wq = (const float*)d_in[21];     const float* bq = (const float*)d_in[22];
  const float* Wk = (const float*)d_in[23];     const float* bk = (const float*)d_in[24];
  const float* Wv = (const float*)d_in[25];     const float* bv = (const float*)d_in[26];
  const float* W_p1 = (const float*)d_in[27];   const float* b_p1 = (const float*)d_in[28];
  const float* W_p2 = (const float*)d_in[29];   const float* b_p2 = (const float*)d_in[30];

  float* y     = (float*)d_out;
  float* confs = (float*)d_out + (size_t)NB * ND;
  float* pad   = confs + 5;

  char* p = (char*)d_ws;
  float* gate_sum = (float*)p;
  float* z   = (float*)(p + 256);
  bf16* kh   = (bf16*)(p + 256 + (size_t)NB * ND * 4);
  bf16* vh   = kh + (size_t)4 * NB * ND;
  bf16* W1F  = vh + (size_t)4 * NB * ND;
  bf16* W2F  = W1F + 384 * 256;
  bf16* WA1F = W2F + 256 * 128;
  bf16* WA2F = WA1F + 256 * 256;
  bf16* WqF  = WA2F + 256 * 128;
  bf16* WkF  = WqF + 128 * 128;
  bf16* WvF  = WkF + 128 * 128;

  hipMemcpyAsync(y, y_init, (size_t)NB * ND * sizeof(float),
                 hipMemcpyDeviceToDevice, stream);
  hipMemsetAsync(gate_sum, 0, 32, stream);
  hipMemsetAsync(z, 0, (size_t)NB * ND * sizeof(float), stream);

  prep_w_frag<<<(384 * 256 + 255) / 256, 256, 0, stream>>>(W_lat1, W1F, 384, 256);
  prep_w_frag<<<(256 * 128 + 255) / 256, 256, 0, stream>>>(W_lat2, W2F, 256, 128);
  prep_w_frag<<<(256 * 256 + 255) / 256, 256, 0, stream>>>(W_ans1, WA1F, 256, 256);
  prep_w_frag<<<(256 * 128 + 255) / 256, 256, 0, stream>>>(W_ans2, WA2F, 256, 128);
  prep_w_frag<<<(128 * 128 + 255) / 256, 256, 0, stream>>>(Wq, WqF, 128, 128);
  prep_w_frag<<<(128 * 128 + 255) / 256, 256, 0, stream>>>(Wk, WkF, 128, 128);
  prep_w_frag<<<(128 * 128 + 255) / 256, 256, 0, stream>>>(Wv, WvF, 128, 128);

  dim3 grid(NB / 32), blk(256);
  for (int k = 0; k < 5; ++k) {
    latent4<<<grid, blk, 0, stream>>>(x, y, z, ln_lat_w, ln_lat_b,
                                      W1F, b_lat1, W2F, b_lat2, ln_z_w, ln_z_b);
    step_tail<<<grid, blk, 0, stream>>>(y, z, av, ln_ans_w, ln_ans_b, ln_z_w, ln_z_b,
                                        WA1F, b_ans1, WA2F, b_ans2,
                                        W_ap, b_ap, W_ag, b_ag,
                                        WqF, bq, WkF, bk, WvF, bv,
                                        gate_sum, kh, vh, k);
  }
  pad_head<<<grid, blk, 0, stream>>>(z, W_p1, b_p1, W_p2, b_p2, pad);
  finalize_confs<<<1, 64, 0, stream>>>(gate_sum, confs);
}